// Round 2
// baseline (589.261 us; speedup 1.0000x reference)
//
#include <hip/hip_runtime.h>

typedef unsigned short u16;
typedef short short8 __attribute__((ext_vector_type(8)));
typedef float f32x4 __attribute__((ext_vector_type(4)));
typedef __bf16 bf16x8 __attribute__((ext_vector_type(8)));

#define SCALE_QK 0.17677669529663687f  // 1/sqrt(32)
#define CB 64                          // batches per chunk
#define CH_M (CB * 196)                // 12544 token-rows per chunk
#define CH_BH (CB * 8)                 // 512 (b,h) pairs per chunk

__device__ __forceinline__ u16 f2b(float f) {
    unsigned int u = __builtin_bit_cast(unsigned int, f);
    u += 0x7fffu + ((u >> 16) & 1u);
    return (u16)(u >> 16);
}

__device__ __forceinline__ f32x4 mfma16(short8 a, short8 b, f32x4 c) {
    return __builtin_amdgcn_mfma_f32_16x16x32_bf16(
        __builtin_bit_cast(bf16x8, a), __builtin_bit_cast(bf16x8, b), c, 0, 0, 0);
}

__device__ __forceinline__ void gload_lds16(const u16* g, u16* l) {
    __builtin_amdgcn_global_load_lds(
        (const __attribute__((address_space(1))) unsigned int*)g,
        (__attribute__((address_space(3))) unsigned int*)l, 16, 0, 0);
}

// ---------------- fp32 -> bf16 convert ----------------
__global__ void cvt_kernel(const float4* __restrict__ in, ushort4* __restrict__ out, int n4) {
    int stride = gridDim.x * blockDim.x;
    for (int i = blockIdx.x * blockDim.x + threadIdx.x; i < n4; i += stride) {
        float4 v = in[i];
        ushort4 o;
        o.x = f2b(v.x); o.y = f2b(v.y); o.z = f2b(v.z); o.w = f2b(v.w);
        out[i] = o;
    }
}

// ---------------- bias matrix expand: bm[h][i][j] = ab[h][idx[i][j]] ----------------
__global__ void biasmat_kernel(const float* __restrict__ ab, const int* __restrict__ idxs,
                               float* __restrict__ bm) {
    int total = 8 * 196 * 196;
    int stride = gridDim.x * blockDim.x;
    for (int i = blockIdx.x * blockDim.x + threadIdx.x; i < total; i += stride) {
        int h = i / (196 * 196);
        int ij = i - h * (196 * 196);
        bm[i] = ab[h * 196 + idxs[ij]];
    }
}

// ---------------- zero vt padding cols 196..223 (chunk buffer, once per launch) ----------------
__global__ void vtpad_kernel(u16* __restrict__ vt) {
    int total = CH_BH * 128 * 28;
    int stride = gridDim.x * blockDim.x;
    for (int i = blockIdx.x * blockDim.x + threadIdx.x; i < total; i += stride) {
        int c = i % 28;
        int r = i / 28;  // bh*128 + d
        vt[(size_t)r * 224 + 196 + c] = 0;
    }
}

// ---------------- bf16 GEMM: C = A(M x K) * Bw(N x K)^T + bias ----------------
// 128x128 tile, 4 waves (64x64 each), BK=64, global_load_lds staging with
// XOR-swizzled LDS layout via pre-swizzled global source.
// EPI==0: route outputs to q/k/vt (qkv GEMM, chunk-local).  EPI==1: fp32 out (proj).
template <int KDIM, int NTILES, int EPI>
__global__ __launch_bounds__(256) void gemm_kernel(
    const u16* __restrict__ A, const u16* __restrict__ Bw, const float* __restrict__ bias,
    u16* __restrict__ o_q, u16* __restrict__ o_k, u16* __restrict__ o_vt,
    float* __restrict__ o_f) {
    __shared__ u16 Alds[128 * 64];
    __shared__ u16 Blds[128 * 64];

    const int bid = blockIdx.x;
    const int tm = bid / NTILES, tn = bid % NTILES;
    const int tid = threadIdx.x, wave = tid >> 6, lane = tid & 63;
    const int l15 = lane & 15, l4 = lane >> 4;
    const int wm = (wave >> 1) * 64, wn = (wave & 1) * 64;

    const u16* Ab = A + (size_t)tm * 128 * KDIM;
    const u16* Bb = Bw + (size_t)tn * 128 * KDIM;

    f32x4 acc[4][4] = {};

    const int rbase = wave * 32 + (lane >> 3);
    const int s_ = lane & 7;

    for (int k0 = 0; k0 < KDIM; k0 += 64) {
#pragma unroll
        for (int i = 0; i < 4; i++) {
            int row = rbase + i * 8;
            int sd = s_ ^ (row & 7);
            gload_lds16(Ab + (size_t)row * KDIM + k0 + sd * 8, &Alds[(wave * 4 + i) * 512]);
        }
#pragma unroll
        for (int i = 0; i < 4; i++) {
            int row = rbase + i * 8;
            int sd = s_ ^ (row & 7);
            gload_lds16(Bb + (size_t)row * KDIM + k0 + sd * 8, &Blds[(wave * 4 + i) * 512]);
        }
        __syncthreads();
#pragma unroll
        for (int ks = 0; ks < 2; ks++) {
            short8 af[4], bfr[4];
#pragma unroll
            for (int t = 0; t < 4; t++) {
                int rowa = wm + t * 16 + l15;
                int bytea = (rowa * 128 + ks * 64 + l4 * 16) ^ ((rowa & 7) << 4);
                af[t] = *reinterpret_cast<const short8*>((const char*)Alds + bytea);
                int rowb = wn + t * 16 + l15;
                int byteb = (rowb * 128 + ks * 64 + l4 * 16) ^ ((rowb & 7) << 4);
                bfr[t] = *reinterpret_cast<const short8*>((const char*)Blds + byteb);
            }
#pragma unroll
            for (int mt = 0; mt < 4; mt++)
#pragma unroll
                for (int nt = 0; nt < 4; nt++)
                    acc[mt][nt] = mfma16(af[mt], bfr[nt], acc[mt][nt]);
        }
        __syncthreads();
    }

    // epilogue
#pragma unroll
    for (int mt = 0; mt < 4; mt++) {
#pragma unroll
        for (int nt = 0; nt < 4; nt++) {
            int gn = tn * 128 + wn + nt * 16 + l15;
            float bv = bias[gn];
#pragma unroll
            for (int r = 0; r < 4; r++) {
                int gm = tm * 128 + wm + mt * 16 + l4 * 4 + r;  // chunk-local token row
                float v = acc[mt][nt][r] + bv;
                if (EPI == 0) {
                    int bb = gm / 196, nn = gm - bb * 196;  // chunk-local batch
                    int h = gn / 192, r2 = gn - h * 192;
                    int bh = bb * 8 + h;                    // chunk-local bh
                    if (r2 < 32)
                        o_q[((size_t)bh * 196 + nn) * 32 + r2] = f2b(v);
                    else if (r2 < 64)
                        o_k[((size_t)bh * 196 + nn) * 32 + (r2 - 32)] = f2b(v);
                    else
                        o_vt[((size_t)bh * 128 + (r2 - 64)) * 224 + nn] = f2b(v);
                } else {
                    o_f[(size_t)gm * 384 + gn] = v;
                }
            }
        }
    }
}

// ---------------- fused attention per chunk-local (b,h) ----------------
// Q,K: [bh][196][32] bf16; Vt: [bh][128][224] bf16 (cols 196.. zeroed);
// bm: [8][196][196] fp32; out (chunk-local): [b*196+n][h*128+d] bf16
__global__ __launch_bounds__(256) void attn_kernel(
    const u16* __restrict__ qb, const u16* __restrict__ kb, const u16* __restrict__ vt,
    const float* __restrict__ bm, u16* __restrict__ out) {
    __shared__ u16 Klds[224 * 40];     // padded stride 40 (80B = 5x16B, aligned)
    __shared__ u16 Vlds[128 * 232];    // Vt rows d, cols k (padded 232 = 29x16B)
    __shared__ u16 Plds[4][16 * 232];  // per-wave P tile

    const int bh = blockIdx.x;  // chunk-local
    const int b = bh >> 3, h = bh & 7;
    const int tid = threadIdx.x, wave = tid >> 6, lane = tid & 63;
    const int l15 = lane & 15, l4 = lane >> 4;

    // stage K (zero-fill rows >= 196)
    const u16* kbase = kb + (size_t)bh * (196 * 32);
    for (int u = tid; u < 896; u += 256) {
        int j = u >> 2, c8 = (u & 3) * 8;
        short8 v = {};
        if (j < 196) v = *reinterpret_cast<const short8*>(kbase + j * 32 + c8);
        *reinterpret_cast<short8*>(&Klds[j * 40 + c8]) = v;
    }
    // stage Vt
    const u16* vbase = vt + (size_t)bh * (128 * 224);
    for (int u = tid; u < 3584; u += 256) {
        int d = u / 28, c8 = (u % 28) * 8;
        *reinterpret_cast<short8*>(&Vlds[d * 232 + c8]) =
            *reinterpret_cast<const short8*>(vbase + d * 224 + c8);
    }
    __syncthreads();

    const float* bmh = bm + h * (196 * 196);
    const u16* qbase = qb + (size_t)bh * (196 * 32);
    u16* P = &Plds[wave][0];

    for (int it = wave; it < 13; it += 4) {
        int i0 = it * 16;
        int qn = i0 + l15; if (qn > 195) qn = 195;
        short8 qf = *reinterpret_cast<const short8*>(qbase + qn * 32 + l4 * 8);

        f32x4 s[13];
#pragma unroll
        for (int jt = 0; jt < 13; jt++) {
            short8 kf = *reinterpret_cast<const short8*>(&Klds[(jt * 16 + l15) * 40 + l4 * 8]);
            f32x4 z = {0.f, 0.f, 0.f, 0.f};
            s[jt] = mfma16(qf, kf, z);
        }

#pragma unroll
        for (int r = 0; r < 4; r++) {
            int gi = i0 + l4 * 4 + r;
            int girow = gi < 196 ? gi : 195;
            float mx = -3e38f;
#pragma unroll
            for (int jt = 0; jt < 13; jt++) {
                int gj = jt * 16 + l15;
                float v = (gj < 196) ? (s[jt][r] * SCALE_QK + bmh[girow * 196 + gj]) : -3e38f;
                s[jt][r] = v;
                mx = fmaxf(mx, v);
            }
            mx = fmaxf(mx, __shfl_xor(mx, 1));
            mx = fmaxf(mx, __shfl_xor(mx, 2));
            mx = fmaxf(mx, __shfl_xor(mx, 4));
            mx = fmaxf(mx, __shfl_xor(mx, 8));
            float sum = 0.f;
#pragma unroll
            for (int jt = 0; jt < 13; jt++) {
                float p = __expf(s[jt][r] - mx);
                s[jt][r] = p;
                sum += p;
            }
            sum += __shfl_xor(sum, 1);
            sum += __shfl_xor(sum, 2);
            sum += __shfl_xor(sum, 4);
            sum += __shfl_xor(sum, 8);
            float inv = 1.f / sum;
#pragma unroll
            for (int jt = 0; jt < 13; jt++) s[jt][r] *= inv;
        }

        // write P (bf16) to per-wave LDS
#pragma unroll
        for (int jt = 0; jt < 13; jt++) {
#pragma unroll
            for (int r = 0; r < 4; r++)
                P[(l4 * 4 + r) * 232 + jt * 16 + l15] = f2b(s[jt][r]);
        }
#pragma unroll
        for (int r = 0; r < 4; r++) P[(l4 * 4 + r) * 232 + 208 + l15] = 0;

        // PV
        f32x4 o[8] = {};
#pragma unroll
        for (int ks = 0; ks < 7; ks++) {
            short8 pf = *reinterpret_cast<const short8*>(&P[l15 * 232 + ks * 32 + l4 * 8]);
#pragma unroll
            for (int dt = 0; dt < 8; dt++) {
                short8 vf = *reinterpret_cast<const short8*>(
                    &Vlds[(dt * 16 + l15) * 232 + ks * 32 + l4 * 8]);
                o[dt] = mfma16(pf, vf, o[dt]);
            }
        }

        // store O as bf16 into chunk-local [token][h*128+d]
        u16* ob = out + ((size_t)b * 196) * 1024 + h * 128;
#pragma unroll
        for (int dt = 0; dt < 8; dt++) {
#pragma unroll
            for (int r = 0; r < 4; r++) {
                int gi = i0 + l4 * 4 + r;
                if (gi < 196) ob[(size_t)gi * 1024 + dt * 16 + l15] = f2b(o[dt][r]);
            }
        }
    }
}

extern "C" void kernel_launch(void* const* d_in, const int* in_sizes, int n_in,
                              void* d_out, int out_size, void* d_ws, size_t ws_size,
                              hipStream_t stream) {
    const float* x = (const float*)d_in[0];
    const float* w_qkv = (const float*)d_in[1];
    const float* b_qkv = (const float*)d_in[2];
    const float* w_proj = (const float*)d_in[3];
    const float* b_proj = (const float*)d_in[4];
    const float* attn_biases = (const float*)d_in[5];
    const int* bias_idxs = (const int*)d_in[6];
    float* out = (float*)d_out;

    char* p = (char*)d_ws;
    auto alloc = [&](size_t bytes) {
        void* r = (void*)p;
        p += (bytes + 255) & ~(size_t)255;
        return r;
    };
    // persistent across chunks (~3.2 MB)
    u16* wqb = (u16*)alloc(1536ull * 384 * 2);
    u16* wpb = (u16*)alloc(384ull * 1024 * 2);
    float* bmat = (float*)alloc(8ull * 196 * 196 * 4);
    // chunk-reused buffers (~77 MB)
    u16* xbc = (u16*)alloc((size_t)CH_M * 384 * 2);
    u16* qc = (u16*)alloc((size_t)CH_BH * 196 * 32 * 2);
    u16* kc = (u16*)alloc((size_t)CH_BH * 196 * 32 * 2);
    u16* vtc = (u16*)alloc((size_t)CH_BH * 128 * 224 * 2);
    u16* aoutc = (u16*)alloc((size_t)CH_M * 1024 * 2);

    // one-time prep
    cvt_kernel<<<576, 256, 0, stream>>>((const float4*)w_qkv, (ushort4*)wqb, 1536 * 384 / 4);
    cvt_kernel<<<384, 256, 0, stream>>>((const float4*)w_proj, (ushort4*)wpb, 384 * 1024 / 4);
    biasmat_kernel<<<1201, 256, 0, stream>>>(attn_biases, bias_idxs, bmat);
    vtpad_kernel<<<1024, 256, 0, stream>>>(vtc);  // pad cols stay 0 for all chunks

    for (int c = 0; c < 4; ++c) {
        const float* xc = x + (size_t)c * CH_M * 384;
        cvt_kernel<<<1024, 256, 0, stream>>>((const float4*)xc, (ushort4*)xbc, CH_M * 384 / 4);
        // qkv GEMM: (12544x384) x (1536x384)^T
        gemm_kernel<384, 12, 0><<<98 * 12, 256, 0, stream>>>(xbc, wqb, b_qkv, qc, kc, vtc, nullptr);
        // attention (512 blocks)
        attn_kernel<<<CH_BH, 256, 0, stream>>>(qc, kc, vtc, bmat, aoutc);
        // proj GEMM: (12544x1024) x (384x1024)^T
        gemm_kernel<1024, 3, 1><<<98 * 3, 256, 0, stream>>>(aoutc, wpb, b_proj, nullptr, nullptr,
                                                            nullptr, out + (size_t)c * CH_M * 384);
    }
}

// Round 3
// 550.624 us; speedup vs baseline: 1.0702x; 1.0702x over previous
//
#include <hip/hip_runtime.h>

typedef unsigned short u16;
typedef short short8 __attribute__((ext_vector_type(8)));
typedef float f32x4 __attribute__((ext_vector_type(4)));
typedef __bf16 bf16x8 __attribute__((ext_vector_type(8)));

#define SCALE_QK 0.17677669529663687f  // 1/sqrt(32)

__device__ __forceinline__ u16 f2b(float f) {
    unsigned int u = __builtin_bit_cast(unsigned int, f);
    u += 0x7fffu + ((u >> 16) & 1u);
    return (u16)(u >> 16);
}

__device__ __forceinline__ f32x4 mfma16(short8 a, short8 b, f32x4 c) {
    return __builtin_amdgcn_mfma_f32_16x16x32_bf16(
        __builtin_bit_cast(bf16x8, a), __builtin_bit_cast(bf16x8, b), c, 0, 0, 0);
}

__device__ __forceinline__ void gload_lds16(const u16* g, u16* l) {
    __builtin_amdgcn_global_load_lds(
        (const __attribute__((address_space(1))) unsigned int*)g,
        (__attribute__((address_space(3))) unsigned int*)l, 16, 0, 0);
}

// ---------------- fp32 -> bf16 convert ----------------
__global__ void cvt_kernel(const float4* __restrict__ in, ushort4* __restrict__ out, int n4) {
    int stride = gridDim.x * blockDim.x;
    for (int i = blockIdx.x * blockDim.x + threadIdx.x; i < n4; i += stride) {
        float4 v = in[i];
        ushort4 o;
        o.x = f2b(v.x); o.y = f2b(v.y); o.z = f2b(v.z); o.w = f2b(v.w);
        out[i] = o;
    }
}

// ---------------- bias matrix expand: bm[h][i][j] = ab[h][idx[i][j]] ----------------
__global__ void biasmat_kernel(const float* __restrict__ ab, const int* __restrict__ idxs,
                               float* __restrict__ bm) {
    int total = 8 * 196 * 196;
    int stride = gridDim.x * blockDim.x;
    for (int i = blockIdx.x * blockDim.x + threadIdx.x; i < total; i += stride) {
        int h = i / (196 * 196);
        int ij = i - h * (196 * 196);
        bm[i] = ab[h * 196 + idxs[ij]];
    }
}

// ---------------- zero vt padding cols 196..223 ----------------
__global__ void vtpad_kernel(u16* __restrict__ vt, int nbh) {
    int total = nbh * 128 * 28;
    int stride = gridDim.x * blockDim.x;
    for (int i = blockIdx.x * blockDim.x + threadIdx.x; i < total; i += stride) {
        int c = i % 28;
        int r = i / 28;  // bh*128 + d
        vt[(size_t)r * 224 + 196 + c] = 0;
    }
}

// ---------------- bf16 GEMM: C = A(M x K) * Bw(N x K)^T + bias ----------------
// 128x128 tile, 4 waves (64x64 each), BK=64, double-buffered LDS with
// counted-vmcnt prefetch pipeline (issue stage(t+1) before compute(t);
// s_waitcnt vmcnt(8) so the prefetch stays in flight across the barrier).
// EPI==0: route outputs to q/k/vt (qkv GEMM, chunk-local).  EPI==1: fp32 out (proj).
template <int KDIM, int NTILES, int EPI>
__global__ __launch_bounds__(256) void gemm_kernel(
    const u16* __restrict__ A, const u16* __restrict__ Bw, const float* __restrict__ bias,
    u16* __restrict__ o_q, u16* __restrict__ o_k, u16* __restrict__ o_vt,
    float* __restrict__ o_f) {
    __shared__ u16 Asl[2][128 * 64];
    __shared__ u16 Bsl[2][128 * 64];

    const int bid = blockIdx.x;
    const int tm = bid / NTILES, tn = bid % NTILES;
    const int tid = threadIdx.x, wave = tid >> 6, lane = tid & 63;
    const int l15 = lane & 15, l4 = lane >> 4;
    const int wm = (wave >> 1) * 64, wn = (wave & 1) * 64;

    const u16* Ab = A + (size_t)tm * 128 * KDIM;
    const u16* Bb = Bw + (size_t)tn * 128 * KDIM;

    f32x4 acc[4][4] = {};

    const int rbase = wave * 32 + (lane >> 3);
    const int s_ = lane & 7;

    // stage one BK=64 tile (A+B) into buffer `buf`: 8 global_load_lds per wave
    auto stage = [&](int buf, int k0) {
#pragma unroll
        for (int i = 0; i < 4; i++) {
            int row = rbase + i * 8;
            int sd = s_ ^ (row & 7);
            gload_lds16(Ab + (size_t)row * KDIM + k0 + sd * 8, &Asl[buf][(wave * 4 + i) * 512]);
            gload_lds16(Bb + (size_t)row * KDIM + k0 + sd * 8, &Bsl[buf][(wave * 4 + i) * 512]);
        }
    };

    constexpr int NT = KDIM / 64;
    stage(0, 0);
#pragma unroll
    for (int t = 0; t < NT; ++t) {
        if (t + 1 < NT) {
            stage((t + 1) & 1, (t + 1) * 64);
            // wait for tile t's 8 loads (the 8 just-issued stay in flight)
            asm volatile("s_waitcnt vmcnt(8)" ::: "memory");
        } else {
            asm volatile("s_waitcnt vmcnt(0)" ::: "memory");
        }
        __builtin_amdgcn_s_barrier();

        const u16* As = Asl[t & 1];
        const u16* Bs = Bsl[t & 1];
#pragma unroll
        for (int ks = 0; ks < 2; ks++) {
            short8 af[4], bfr[4];
#pragma unroll
            for (int u = 0; u < 4; u++) {
                int rowa = wm + u * 16 + l15;
                int bytea = (rowa * 128 + ks * 64 + l4 * 16) ^ ((rowa & 7) << 4);
                af[u] = *reinterpret_cast<const short8*>((const char*)As + bytea);
                int rowb = wn + u * 16 + l15;
                int byteb = (rowb * 128 + ks * 64 + l4 * 16) ^ ((rowb & 7) << 4);
                bfr[u] = *reinterpret_cast<const short8*>((const char*)Bs + byteb);
            }
            __builtin_amdgcn_s_setprio(1);
#pragma unroll
            for (int mt = 0; mt < 4; mt++)
#pragma unroll
                for (int nt = 0; nt < 4; nt++)
                    acc[mt][nt] = mfma16(af[mt], bfr[nt], acc[mt][nt]);
            __builtin_amdgcn_s_setprio(0);
        }
        __builtin_amdgcn_s_barrier();  // all waves done reading buf[t&1]; safe to restage at t+1
    }

    // epilogue
#pragma unroll
    for (int mt = 0; mt < 4; mt++) {
#pragma unroll
        for (int nt = 0; nt < 4; nt++) {
            int gn = tn * 128 + wn + nt * 16 + l15;
            float bv = bias[gn];
#pragma unroll
            for (int r = 0; r < 4; r++) {
                int gm = tm * 128 + wm + mt * 16 + l4 * 4 + r;  // chunk-local token row
                float v = acc[mt][nt][r] + bv;
                if (EPI == 0) {
                    int bb = gm / 196, nn = gm - bb * 196;  // chunk-local batch
                    int h = gn / 192, r2 = gn - h * 192;
                    int bh = bb * 8 + h;                    // chunk-local bh
                    if (r2 < 32)
                        o_q[((size_t)bh * 196 + nn) * 32 + r2] = f2b(v);
                    else if (r2 < 64)
                        o_k[((size_t)bh * 196 + nn) * 32 + (r2 - 32)] = f2b(v);
                    else
                        o_vt[((size_t)bh * 128 + (r2 - 64)) * 224 + nn] = f2b(v);
                } else {
                    o_f[(size_t)gm * 384 + gn] = v;
                }
            }
        }
    }
}

// ---------------- fused attention per chunk-local (b,h) ----------------
// Q,K: [bh][196][32] bf16; Vt: [bh][128][224] bf16 (cols 196.. zeroed);
// bm: [8][196][196] fp32; out (chunk-local): [b*196+n][h*128+d] bf16
__global__ __launch_bounds__(256) void attn_kernel(
    const u16* __restrict__ qb, const u16* __restrict__ kb, const u16* __restrict__ vt,
    const float* __restrict__ bm, u16* __restrict__ out) {
    __shared__ u16 Klds[224 * 40];     // padded stride 40 (80B = 5x16B, aligned)
    __shared__ u16 Vlds[128 * 232];    // Vt rows d, cols k (padded 232 = 29x16B)
    __shared__ u16 Plds[4][16 * 232];  // per-wave P tile

    const int bh = blockIdx.x;  // chunk-local
    const int b = bh >> 3, h = bh & 7;
    const int tid = threadIdx.x, wave = tid >> 6, lane = tid & 63;
    const int l15 = lane & 15, l4 = lane >> 4;

    // stage K (zero-fill rows >= 196)
    const u16* kbase = kb + (size_t)bh * (196 * 32);
    for (int u = tid; u < 896; u += 256) {
        int j = u >> 2, c8 = (u & 3) * 8;
        short8 v = {};
        if (j < 196) v = *reinterpret_cast<const short8*>(kbase + j * 32 + c8);
        *reinterpret_cast<short8*>(&Klds[j * 40 + c8]) = v;
    }
    // stage Vt
    const u16* vbase = vt + (size_t)bh * (128 * 224);
    for (int u = tid; u < 3584; u += 256) {
        int d = u / 28, c8 = (u % 28) * 8;
        *reinterpret_cast<short8*>(&Vlds[d * 232 + c8]) =
            *reinterpret_cast<const short8*>(vbase + d * 224 + c8);
    }
    __syncthreads();

    const float* bmh = bm + h * (196 * 196);
    const u16* qbase = qb + (size_t)bh * (196 * 32);
    u16* P = &Plds[wave][0];

    for (int it = wave; it < 13; it += 4) {
        int i0 = it * 16;
        int qn = i0 + l15; if (qn > 195) qn = 195;
        short8 qf = *reinterpret_cast<const short8*>(qbase + qn * 32 + l4 * 8);

        f32x4 s[13];
#pragma unroll
        for (int jt = 0; jt < 13; jt++) {
            short8 kf = *reinterpret_cast<const short8*>(&Klds[(jt * 16 + l15) * 40 + l4 * 8]);
            f32x4 z = {0.f, 0.f, 0.f, 0.f};
            s[jt] = mfma16(qf, kf, z);
        }

#pragma unroll
        for (int r = 0; r < 4; r++) {
            int gi = i0 + l4 * 4 + r;
            int girow = gi < 196 ? gi : 195;
            float mx = -3e38f;
#pragma unroll
            for (int jt = 0; jt < 13; jt++) {
                int gj = jt * 16 + l15;
                float v = (gj < 196) ? (s[jt][r] * SCALE_QK + bmh[girow * 196 + gj]) : -3e38f;
                s[jt][r] = v;
                mx = fmaxf(mx, v);
            }
            mx = fmaxf(mx, __shfl_xor(mx, 1));
            mx = fmaxf(mx, __shfl_xor(mx, 2));
            mx = fmaxf(mx, __shfl_xor(mx, 4));
            mx = fmaxf(mx, __shfl_xor(mx, 8));
            float sum = 0.f;
#pragma unroll
            for (int jt = 0; jt < 13; jt++) {
                float p = __expf(s[jt][r] - mx);
                s[jt][r] = p;
                sum += p;
            }
            sum += __shfl_xor(sum, 1);
            sum += __shfl_xor(sum, 2);
            sum += __shfl_xor(sum, 4);
            sum += __shfl_xor(sum, 8);
            float inv = 1.f / sum;
#pragma unroll
            for (int jt = 0; jt < 13; jt++) s[jt][r] *= inv;
        }

        // write P (bf16) to per-wave LDS
#pragma unroll
        for (int jt = 0; jt < 13; jt++) {
#pragma unroll
            for (int r = 0; r < 4; r++)
                P[(l4 * 4 + r) * 232 + jt * 16 + l15] = f2b(s[jt][r]);
        }
#pragma unroll
        for (int r = 0; r < 4; r++) P[(l4 * 4 + r) * 232 + 208 + l15] = 0;

        // PV
        f32x4 o[8] = {};
#pragma unroll
        for (int ks = 0; ks < 7; ks++) {
            short8 pf = *reinterpret_cast<const short8*>(&P[l15 * 232 + ks * 32 + l4 * 8]);
#pragma unroll
            for (int dt = 0; dt < 8; dt++) {
                short8 vf = *reinterpret_cast<const short8*>(
                    &Vlds[(dt * 16 + l15) * 232 + ks * 32 + l4 * 8]);
                o[dt] = mfma16(pf, vf, o[dt]);
            }
        }

        // store O as bf16 into chunk-local [token][h*128+d]
        u16* ob = out + ((size_t)b * 196) * 1024 + h * 128;
#pragma unroll
        for (int dt = 0; dt < 8; dt++) {
#pragma unroll
            for (int r = 0; r < 4; r++) {
                int gi = i0 + l4 * 4 + r;
                if (gi < 196) ob[(size_t)gi * 1024 + dt * 16 + l15] = f2b(o[dt][r]);
            }
        }
    }
}

extern "C" void kernel_launch(void* const* d_in, const int* in_sizes, int n_in,
                              void* d_out, int out_size, void* d_ws, size_t ws_size,
                              hipStream_t stream) {
    const float* x = (const float*)d_in[0];
    const float* w_qkv = (const float*)d_in[1];
    const float* b_qkv = (const float*)d_in[2];
    const float* w_proj = (const float*)d_in[3];
    const float* b_proj = (const float*)d_in[4];
    const float* attn_biases = (const float*)d_in[5];
    const int* bias_idxs = (const int*)d_in[6];
    float* out = (float*)d_out;

    // runtime workspace plan (ws_size is fixed across calls -> deterministic)
    const size_t MB = 1ull << 20;
    int nc;            // chunks over the batch dim for cvt/qkv/attn
    bool full_aout;    // aout holds all 256 batches -> single proj dispatch
    if (ws_size >= 330 * MB)      { nc = 1; full_aout = true; }
    else if (ws_size >= 168 * MB) { nc = 4; full_aout = true; }
    else                          { nc = 4; full_aout = false; }
    const int cb = 256 / nc;            // batches per chunk
    const size_t chm = (size_t)cb * 196;
    const int chbh = cb * 8;

    char* p = (char*)d_ws;
    auto alloc = [&](size_t bytes) {
        void* r = (void*)p;
        p += (bytes + 255) & ~(size_t)255;
        return r;
    };
    // persistent (~3.2 MB)
    u16* wqb = (u16*)alloc(1536ull * 384 * 2);
    u16* wpb = (u16*)alloc(384ull * 1024 * 2);
    float* bmat = (float*)alloc(8ull * 196 * 196 * 4);
    // chunk buffers
    u16* xbc = (u16*)alloc(chm * 384 * 2);
    u16* qc = (u16*)alloc((size_t)chbh * 196 * 32 * 2);
    u16* kc = (u16*)alloc((size_t)chbh * 196 * 32 * 2);
    u16* vtc = (u16*)alloc((size_t)chbh * 128 * 224 * 2);
    u16* aout_b = (u16*)alloc((full_aout ? 50176ull : chm) * 1024 * 2);

    // one-time prep
    cvt_kernel<<<576, 256, 0, stream>>>((const float4*)w_qkv, (ushort4*)wqb, 1536 * 384 / 4);
    cvt_kernel<<<384, 256, 0, stream>>>((const float4*)w_proj, (ushort4*)wpb, 384 * 1024 / 4);
    biasmat_kernel<<<1201, 256, 0, stream>>>(attn_biases, bias_idxs, bmat);
    vtpad_kernel<<<1024, 256, 0, stream>>>(vtc, chbh);  // pad cols stay 0 across chunks

    const int qkv_grid = (int)(chm / 128) * 12;
    const int proj_grid_chunk = (int)(chm / 128) * 3;

    for (int c = 0; c < nc; ++c) {
        const float* xc = x + (size_t)c * chm * 384;
        cvt_kernel<<<1024, 256, 0, stream>>>((const float4*)xc, (ushort4*)xbc,
                                             (int)(chm * 384 / 4));
        gemm_kernel<384, 12, 0><<<qkv_grid, 256, 0, stream>>>(xbc, wqb, b_qkv, qc, kc, vtc,
                                                              nullptr);
        u16* aoutc = aout_b + (full_aout ? (size_t)c * chm * 1024 : 0);
        attn_kernel<<<chbh, 256, 0, stream>>>(qc, kc, vtc, bmat, aoutc);
        if (!full_aout) {
            gemm_kernel<1024, 3, 1><<<proj_grid_chunk, 256, 0, stream>>>(
                aoutc, wpb, b_proj, nullptr, nullptr, nullptr, out + (size_t)c * chm * 384);
        }
    }
    if (full_aout) {
        gemm_kernel<1024, 3, 1><<<392 * 3, 256, 0, stream>>>(aout_b, wpb, b_proj, nullptr,
                                                             nullptr, nullptr, out);
    }
}

// Round 4
// 490.460 us; speedup vs baseline: 1.2014x; 1.1227x over previous
//
#include <hip/hip_runtime.h>

typedef unsigned short u16;
typedef short short8 __attribute__((ext_vector_type(8)));
typedef float f32x4 __attribute__((ext_vector_type(4)));
typedef __bf16 bf16x8 __attribute__((ext_vector_type(8)));

#define SCALE_QK 0.17677669529663687f  // 1/sqrt(32)

__device__ __forceinline__ u16 f2b(float f) {
    unsigned int u = __builtin_bit_cast(unsigned int, f);
    u += 0x7fffu + ((u >> 16) & 1u);
    return (u16)(u >> 16);
}

__device__ __forceinline__ f32x4 mfma16(short8 a, short8 b, f32x4 c) {
    return __builtin_amdgcn_mfma_f32_16x16x32_bf16(
        __builtin_bit_cast(bf16x8, a), __builtin_bit_cast(bf16x8, b), c, 0, 0, 0);
}

__device__ __forceinline__ void gload_lds16(const u16* g, u16* l) {
    __builtin_amdgcn_global_load_lds(
        (const __attribute__((address_space(1))) unsigned int*)g,
        (__attribute__((address_space(3))) unsigned int*)l, 16, 0, 0);
}

// bijective XCD-chunked block-id swizzle (m204): round-robin -> contiguous per XCD
__device__ __forceinline__ int xcd_swizzle(int bid, int nwg) {
    int qd = nwg >> 3, rm = nwg & 7;
    int xcd = bid & 7, lo = bid >> 3;
    return (xcd < rm ? xcd * (qd + 1) : rm * (qd + 1) + (xcd - rm) * qd) + lo;
}

// ---------------- fp32 -> bf16 convert ----------------
__global__ void cvt_kernel(const float4* __restrict__ in, ushort4* __restrict__ out, int n4) {
    int stride = gridDim.x * blockDim.x;
    for (int i = blockIdx.x * blockDim.x + threadIdx.x; i < n4; i += stride) {
        float4 v = in[i];
        ushort4 o;
        o.x = f2b(v.x); o.y = f2b(v.y); o.z = f2b(v.z); o.w = f2b(v.w);
        out[i] = o;
    }
}

// ---------------- bias matrix expand: bm[h][i][j] = ab[h][idx[i][j]] ----------------
__global__ void biasmat_kernel(const float* __restrict__ ab, const int* __restrict__ idxs,
                               float* __restrict__ bm) {
    int total = 8 * 196 * 196;
    int stride = gridDim.x * blockDim.x;
    for (int i = blockIdx.x * blockDim.x + threadIdx.x; i < total; i += stride) {
        int h = i / (196 * 196);
        int ij = i - h * (196 * 196);
        bm[i] = ab[h * 196 + idxs[ij]];
    }
}

// ---------------- bf16 GEMM: C = A(M x K) * Bw(N x K)^T + bias ----------------
// 128x128 tile, 4 waves (64x64 each), BK=64, double-buffered LDS with
// counted-vmcnt prefetch pipeline. XCD-chunked swizzle for A-panel L2 locality.
// EPI==0: route outputs to q/k/v (qkv GEMM, chunk-local, all coalesced).
// EPI==1: fp32 out (proj).
template <int KDIM, int NTILES, int EPI>
__global__ __launch_bounds__(256) void gemm_kernel(
    const u16* __restrict__ A, const u16* __restrict__ Bw, const float* __restrict__ bias,
    u16* __restrict__ o_q, u16* __restrict__ o_k, u16* __restrict__ o_v,
    float* __restrict__ o_f) {
    __shared__ u16 Asl[2][128 * 64];
    __shared__ u16 Bsl[2][128 * 64];

    const int wg = xcd_swizzle(blockIdx.x, gridDim.x);
    const int tm = wg / NTILES, tn = wg % NTILES;
    const int tid = threadIdx.x, wave = tid >> 6, lane = tid & 63;
    const int l15 = lane & 15, l4 = lane >> 4;
    const int wm = (wave >> 1) * 64, wn = (wave & 1) * 64;

    const u16* Ab = A + (size_t)tm * 128 * KDIM;
    const u16* Bb = Bw + (size_t)tn * 128 * KDIM;

    f32x4 acc[4][4] = {};

    const int rbase = wave * 32 + (lane >> 3);
    const int s_ = lane & 7;

    // stage one BK=64 tile (A+B) into buffer `buf`: 8 global_load_lds per wave
    auto stage = [&](int buf, int k0) {
#pragma unroll
        for (int i = 0; i < 4; i++) {
            int row = rbase + i * 8;
            int sd = s_ ^ (row & 7);
            gload_lds16(Ab + (size_t)row * KDIM + k0 + sd * 8, &Asl[buf][(wave * 4 + i) * 512]);
            gload_lds16(Bb + (size_t)row * KDIM + k0 + sd * 8, &Bsl[buf][(wave * 4 + i) * 512]);
        }
    };

    constexpr int NT = KDIM / 64;
    stage(0, 0);
#pragma unroll
    for (int t = 0; t < NT; ++t) {
        if (t + 1 < NT) {
            stage((t + 1) & 1, (t + 1) * 64);
            asm volatile("s_waitcnt vmcnt(8)" ::: "memory");  // tile t landed; t+1 in flight
        } else {
            asm volatile("s_waitcnt vmcnt(0)" ::: "memory");
        }
        __builtin_amdgcn_s_barrier();

        const u16* As = Asl[t & 1];
        const u16* Bs = Bsl[t & 1];
#pragma unroll
        for (int ks = 0; ks < 2; ks++) {
            short8 af[4], bfr[4];
#pragma unroll
            for (int u = 0; u < 4; u++) {
                int rowa = wm + u * 16 + l15;
                int bytea = (rowa * 128 + ks * 64 + l4 * 16) ^ ((rowa & 7) << 4);
                af[u] = *reinterpret_cast<const short8*>((const char*)As + bytea);
                int rowb = wn + u * 16 + l15;
                int byteb = (rowb * 128 + ks * 64 + l4 * 16) ^ ((rowb & 7) << 4);
                bfr[u] = *reinterpret_cast<const short8*>((const char*)Bs + byteb);
            }
            __builtin_amdgcn_s_setprio(1);
#pragma unroll
            for (int mt = 0; mt < 4; mt++)
#pragma unroll
                for (int nt = 0; nt < 4; nt++)
                    acc[mt][nt] = mfma16(af[mt], bfr[nt], acc[mt][nt]);
            __builtin_amdgcn_s_setprio(0);
        }
        __builtin_amdgcn_s_barrier();
    }

    // epilogue (all stores coalesced: 16 consecutive lanes -> consecutive gn)
#pragma unroll
    for (int mt = 0; mt < 4; mt++) {
#pragma unroll
        for (int nt = 0; nt < 4; nt++) {
            int gn = tn * 128 + wn + nt * 16 + l15;
            float bv = bias[gn];
#pragma unroll
            for (int r = 0; r < 4; r++) {
                int gm = tm * 128 + wm + mt * 16 + l4 * 4 + r;  // chunk-local token row
                float v = acc[mt][nt][r] + bv;
                if (EPI == 0) {
                    int bb = gm / 196, nn = gm - bb * 196;  // chunk-local batch
                    int h = gn / 192, r2 = gn - h * 192;
                    int bh = bb * 8 + h;                    // chunk-local bh
                    if (r2 < 32)
                        o_q[((size_t)bh * 196 + nn) * 32 + r2] = f2b(v);
                    else if (r2 < 64)
                        o_k[((size_t)bh * 196 + nn) * 32 + (r2 - 32)] = f2b(v);
                    else
                        o_v[((size_t)bh * 196 + nn) * 128 + (r2 - 64)] = f2b(v);
                } else {
                    o_f[(size_t)gm * 384 + gn] = v;
                }
            }
        }
    }
}

// ---------------- fused attention per chunk-local (b,h) ----------------
// Q,K: [bh][196][32] bf16; V: [bh][196][128] bf16 row-major (transposed in-LDS);
// bm: [8][196][196] fp32; out (chunk-local): [b*196+n][h*128+d] bf16
__global__ __launch_bounds__(256) void attn_kernel(
    const u16* __restrict__ qb, const u16* __restrict__ kb, const u16* __restrict__ vb,
    const float* __restrict__ bm, u16* __restrict__ out) {
    __shared__ u16 Klds[224 * 40];     // padded stride 40 (80B = 5x16B, aligned)
    __shared__ u16 Vlds[128 * 232];    // V^T: rows d, cols k (padded 232 = 29x16B)
    __shared__ u16 Plds[4][16 * 232];  // per-wave P tile

    const int bh = blockIdx.x;  // chunk-local
    const int b = bh >> 3, h = bh & 7;
    const int tid = threadIdx.x, wave = tid >> 6, lane = tid & 63;
    const int l15 = lane & 15, l4 = lane >> 4;

    // zero Vlds (covers k >= 196 padding)
    for (int u = tid; u < (128 * 232) / 8; u += 256)
        reinterpret_cast<short8*>(Vlds)[u] = short8{};
    // stage K (zero-fill rows >= 196)
    const u16* kbase = kb + (size_t)bh * (196 * 32);
    for (int u = tid; u < 896; u += 256) {
        int j = u >> 2, c8 = (u & 3) * 8;
        short8 v = {};
        if (j < 196) v = *reinterpret_cast<const short8*>(kbase + j * 32 + c8);
        *reinterpret_cast<short8*>(&Klds[j * 40 + c8]) = v;
    }
    __syncthreads();
    // transposed V stage: V[k][d] (coalesced read) -> Vlds[d][k]
    const u16* vbase = vb + (size_t)bh * (196 * 128);
    for (int u0 = tid; u0 < 3136; u0 += 256) {  // 3136 = 196*128/8
        int k = u0 >> 4;
        int d0 = (u0 & 15) * 8;
        short8 vv = *reinterpret_cast<const short8*>(vbase + k * 128 + d0);
#pragma unroll
        for (int j = 0; j < 8; j++) Vlds[(d0 + j) * 232 + k] = (u16)vv[j];
    }
    __syncthreads();

    const float* bmh = bm + h * (196 * 196);
    const u16* qbase = qb + (size_t)bh * (196 * 32);
    u16* P = &Plds[wave][0];

    for (int it = wave; it < 13; it += 4) {
        int i0 = it * 16;
        int qn = i0 + l15; if (qn > 195) qn = 195;
        short8 qf = *reinterpret_cast<const short8*>(qbase + qn * 32 + l4 * 8);

        f32x4 s[13];
#pragma unroll
        for (int jt = 0; jt < 13; jt++) {
            short8 kf = *reinterpret_cast<const short8*>(&Klds[(jt * 16 + l15) * 40 + l4 * 8]);
            f32x4 z = {0.f, 0.f, 0.f, 0.f};
            s[jt] = mfma16(qf, kf, z);
        }

#pragma unroll
        for (int r = 0; r < 4; r++) {
            int gi = i0 + l4 * 4 + r;
            int girow = gi < 196 ? gi : 195;
            float mx = -3e38f;
#pragma unroll
            for (int jt = 0; jt < 13; jt++) {
                int gj = jt * 16 + l15;
                float v = (gj < 196) ? (s[jt][r] * SCALE_QK + bmh[girow * 196 + gj]) : -3e38f;
                s[jt][r] = v;
                mx = fmaxf(mx, v);
            }
            mx = fmaxf(mx, __shfl_xor(mx, 1));
            mx = fmaxf(mx, __shfl_xor(mx, 2));
            mx = fmaxf(mx, __shfl_xor(mx, 4));
            mx = fmaxf(mx, __shfl_xor(mx, 8));
            float sum = 0.f;
#pragma unroll
            for (int jt = 0; jt < 13; jt++) {
                float p = __expf(s[jt][r] - mx);
                s[jt][r] = p;
                sum += p;
            }
            sum += __shfl_xor(sum, 1);
            sum += __shfl_xor(sum, 2);
            sum += __shfl_xor(sum, 4);
            sum += __shfl_xor(sum, 8);
            float inv = 1.f / sum;
#pragma unroll
            for (int jt = 0; jt < 13; jt++) s[jt][r] *= inv;
        }

        // write P (bf16) to per-wave LDS
#pragma unroll
        for (int jt = 0; jt < 13; jt++) {
#pragma unroll
            for (int r = 0; r < 4; r++)
                P[(l4 * 4 + r) * 232 + jt * 16 + l15] = f2b(s[jt][r]);
        }
#pragma unroll
        for (int r = 0; r < 4; r++) P[(l4 * 4 + r) * 232 + 208 + l15] = 0;

        // PV
        f32x4 o[8] = {};
#pragma unroll
        for (int ks = 0; ks < 7; ks++) {
            short8 pf = *reinterpret_cast<const short8*>(&P[l15 * 232 + ks * 32 + l4 * 8]);
#pragma unroll
            for (int dt = 0; dt < 8; dt++) {
                short8 vf = *reinterpret_cast<const short8*>(
                    &Vlds[(dt * 16 + l15) * 232 + ks * 32 + l4 * 8]);
                o[dt] = mfma16(pf, vf, o[dt]);
            }
        }

        // store O as bf16 into chunk-local [token][h*128+d]
        u16* ob = out + ((size_t)b * 196) * 1024 + h * 128;
#pragma unroll
        for (int dt = 0; dt < 8; dt++) {
#pragma unroll
            for (int r = 0; r < 4; r++) {
                int gi = i0 + l4 * 4 + r;
                if (gi < 196) ob[(size_t)gi * 1024 + dt * 16 + l15] = f2b(o[dt][r]);
            }
        }
    }
}

extern "C" void kernel_launch(void* const* d_in, const int* in_sizes, int n_in,
                              void* d_out, int out_size, void* d_ws, size_t ws_size,
                              hipStream_t stream) {
    const float* x = (const float*)d_in[0];
    const float* w_qkv = (const float*)d_in[1];
    const float* b_qkv = (const float*)d_in[2];
    const float* w_proj = (const float*)d_in[3];
    const float* b_proj = (const float*)d_in[4];
    const float* attn_biases = (const float*)d_in[5];
    const int* bias_idxs = (const int*)d_in[6];
    float* out = (float*)d_out;

    // runtime workspace plan (ws_size fixed across calls -> deterministic)
    const size_t MB = 1ull << 20;
    int nc;          // chunks over the batch dim
    bool full_aout;  // aout holds all 256 batches -> single proj dispatch
    if (ws_size >= 310 * MB)      { nc = 1; full_aout = true; }
    else if (ws_size >= 165 * MB) { nc = 4; full_aout = true; }
    else                          { nc = 4; full_aout = false; }
    const int cb = 256 / nc;  // batches per chunk
    const size_t chm = (size_t)cb * 196;
    const int chbh = cb * 8;

    char* p = (char*)d_ws;
    auto alloc = [&](size_t bytes) {
        void* r = (void*)p;
        p += (bytes + 255) & ~(size_t)255;
        return r;
    };
    // persistent (~3.2 MB)
    u16* wqb = (u16*)alloc(1536ull * 384 * 2);
    u16* wpb = (u16*)alloc(384ull * 1024 * 2);
    float* bmat = (float*)alloc(8ull * 196 * 196 * 4);
    // chunk buffers
    u16* xbc = (u16*)alloc(chm * 384 * 2);
    u16* qc = (u16*)alloc((size_t)chbh * 196 * 32 * 2);
    u16* kc = (u16*)alloc((size_t)chbh * 196 * 32 * 2);
    u16* vc = (u16*)alloc((size_t)chbh * 196 * 128 * 2);
    u16* aout_b = (u16*)alloc((full_aout ? 50176ull : chm) * 1024 * 2);

    // one-time prep
    cvt_kernel<<<576, 256, 0, stream>>>((const float4*)w_qkv, (ushort4*)wqb, 1536 * 384 / 4);
    cvt_kernel<<<384, 256, 0, stream>>>((const float4*)w_proj, (ushort4*)wpb, 384 * 1024 / 4);
    biasmat_kernel<<<1201, 256, 0, stream>>>(attn_biases, bias_idxs, bmat);

    const int qkv_grid = (int)(chm / 128) * 12;
    const int proj_grid_chunk = (int)(chm / 128) * 3;

    for (int c = 0; c < nc; ++c) {
        const float* xc = x + (size_t)c * chm * 384;
        cvt_kernel<<<1024, 256, 0, stream>>>((const float4*)xc, (ushort4*)xbc,
                                             (int)(chm * 384 / 4));
        gemm_kernel<384, 12, 0><<<qkv_grid, 256, 0, stream>>>(xbc, wqb, b_qkv, qc, kc, vc,
                                                              nullptr);
        u16* aoutc = aout_b + (full_aout ? (size_t)c * chm * 1024 : 0);
        attn_kernel<<<chbh, 256, 0, stream>>>(qc, kc, vc, bmat, aoutc);
        if (!full_aout) {
            gemm_kernel<1024, 3, 1><<<proj_grid_chunk, 256, 0, stream>>>(
                aoutc, wpb, b_proj, nullptr, nullptr, nullptr, out + (size_t)c * chm * 384);
        }
    }
    if (full_aout) {
        gemm_kernel<1024, 3, 1><<<392 * 3, 256, 0, stream>>>(aout_b, wpb, b_proj, nullptr,
                                                             nullptr, nullptr, out);
    }
}

// Round 5
// 406.226 us; speedup vs baseline: 1.4506x; 1.2074x over previous
//
#include <hip/hip_runtime.h>

typedef unsigned short u16;
typedef short short8 __attribute__((ext_vector_type(8)));
typedef float f32x4 __attribute__((ext_vector_type(4)));
typedef __bf16 bf16x8 __attribute__((ext_vector_type(8)));

#define SCALE_QK 0.17677669529663687f  // 1/sqrt(32)

__device__ __forceinline__ u16 f2b(float f) {
    unsigned int u = __builtin_bit_cast(unsigned int, f);
    u += 0x7fffu + ((u >> 16) & 1u);
    return (u16)(u >> 16);
}

__device__ __forceinline__ f32x4 mfma16(short8 a, short8 b, f32x4 c) {
    return __builtin_amdgcn_mfma_f32_16x16x32_bf16(
        __builtin_bit_cast(bf16x8, a), __builtin_bit_cast(bf16x8, b), c, 0, 0, 0);
}

__device__ __forceinline__ void gload_lds16(const u16* g, u16* l) {
    __builtin_amdgcn_global_load_lds(
        (const __attribute__((address_space(1))) unsigned int*)g,
        (__attribute__((address_space(3))) unsigned int*)l, 16, 0, 0);
}

// bijective XCD-chunked block-id swizzle (m204)
__device__ __forceinline__ int xcd_swizzle(int bid, int nwg) {
    int qd = nwg >> 3, rm = nwg & 7;
    int xcd = bid & 7, lo = bid >> 3;
    return (xcd < rm ? xcd * (qd + 1) : rm * (qd + 1) + (xcd - rm) * qd) + lo;
}

// ---------------- fp32 -> bf16 convert ----------------
__global__ void cvt_kernel(const float4* __restrict__ in, ushort4* __restrict__ out, int n4) {
    int stride = gridDim.x * blockDim.x;
    for (int i = blockIdx.x * blockDim.x + threadIdx.x; i < n4; i += stride) {
        float4 v = in[i];
        ushort4 o;
        o.x = f2b(v.x); o.y = f2b(v.y); o.z = f2b(v.z); o.w = f2b(v.w);
        out[i] = o;
    }
}

// ---------------- bias matrix expand: bm[h][i][j] = ab[h][idx[i][j]] ----------------
__global__ void biasmat_kernel(const float* __restrict__ ab, const int* __restrict__ idxs,
                               float* __restrict__ bm) {
    int total = 8 * 196 * 196;
    int stride = gridDim.x * blockDim.x;
    for (int i = blockIdx.x * blockDim.x + threadIdx.x; i < total; i += stride) {
        int h = i / (196 * 196);
        int ij = i - h * (196 * 196);
        bm[i] = ab[h * 196 + idxs[ij]];
    }
}

// ---------------- bf16 GEMM: C = A(M x K) * Bw(N x K)^T + bias ----------------
// 128x128 tile, 4 waves (64x64 each), BK=32 (LDS 32KB -> 4-5 blocks/CU),
// double-buffered counted-vmcnt pipeline, XCD-chunked swizzle.
// LDS layout: [row][32] u16, row stride 64B; bank-swizzle byte ^= ((row&3)<<4).
// EPI==0: route outputs to q/k/v (qkv, chunk-local).  EPI==1: fp32 out (proj).
template <int KDIM, int NTILES, int EPI>
__global__ __launch_bounds__(256) void gemm_kernel(
    const u16* __restrict__ A, const u16* __restrict__ Bw, const float* __restrict__ bias,
    u16* __restrict__ o_q, u16* __restrict__ o_k, u16* __restrict__ o_v,
    float* __restrict__ o_f) {
    __shared__ u16 Asl[2][128 * 32];
    __shared__ u16 Bsl[2][128 * 32];

    const int wg = xcd_swizzle(blockIdx.x, gridDim.x);
    const int tm = wg / NTILES, tn = wg % NTILES;
    const int tid = threadIdx.x, wave = tid >> 6, lane = tid & 63;
    const int l15 = lane & 15, l4 = lane >> 4;
    const int wm = (wave >> 1) * 64, wn = (wave & 1) * 64;

    const u16* Ab = A + (size_t)tm * 128 * KDIM;
    const u16* Bb = Bw + (size_t)tn * 128 * KDIM;

    f32x4 acc[4][4] = {};

    // stage one BK=32 tile (A+B): 2+2 global_load_lds per wave.
    // lane l covers row = w*32 + i*16 + (l>>2), col-chunk position (l&3);
    // source chunk pre-swizzled: sc = (l&3) ^ (row&3).
    auto stage = [&](int buf, int k0) {
#pragma unroll
        for (int i = 0; i < 2; i++) {
            int row = wave * 32 + i * 16 + (lane >> 2);
            int sc = (lane & 3) ^ (row & 3);
            gload_lds16(Ab + (size_t)row * KDIM + k0 + sc * 8,
                        &Asl[buf][(wave * 32 + i * 16) * 32]);
            gload_lds16(Bb + (size_t)row * KDIM + k0 + sc * 8,
                        &Bsl[buf][(wave * 32 + i * 16) * 32]);
        }
    };

    constexpr int NT = KDIM / 32;
    stage(0, 0);
#pragma unroll
    for (int t = 0; t < NT; ++t) {
        if (t + 1 < NT) {
            stage((t + 1) & 1, (t + 1) * 32);
            asm volatile("s_waitcnt vmcnt(4)" ::: "memory");  // tile t landed; t+1 in flight
        } else {
            asm volatile("s_waitcnt vmcnt(0)" ::: "memory");
        }
        __builtin_amdgcn_s_barrier();

        const char* As = (const char*)Asl[t & 1];
        const char* Bs = (const char*)Bsl[t & 1];
        short8 af[4], bfr[4];
#pragma unroll
        for (int u = 0; u < 4; u++) {
            int rowa = wm + u * 16 + l15;
            int bytea = rowa * 64 + ((l4 * 16) ^ ((rowa & 3) << 4));
            af[u] = *reinterpret_cast<const short8*>(As + bytea);
            int rowb = wn + u * 16 + l15;
            int byteb = rowb * 64 + ((l4 * 16) ^ ((rowb & 3) << 4));
            bfr[u] = *reinterpret_cast<const short8*>(Bs + byteb);
        }
        __builtin_amdgcn_s_setprio(1);
#pragma unroll
        for (int mt = 0; mt < 4; mt++)
#pragma unroll
            for (int nt = 0; nt < 4; nt++)
                acc[mt][nt] = mfma16(af[mt], bfr[nt], acc[mt][nt]);
        __builtin_amdgcn_s_setprio(0);
        __builtin_amdgcn_s_barrier();
    }

    // epilogue (all stores coalesced over l15)
#pragma unroll
    for (int mt = 0; mt < 4; mt++) {
#pragma unroll
        for (int nt = 0; nt < 4; nt++) {
            int gn = tn * 128 + wn + nt * 16 + l15;
            float bv = bias[gn];
#pragma unroll
            for (int r = 0; r < 4; r++) {
                int gm = tm * 128 + wm + mt * 16 + l4 * 4 + r;  // chunk-local token row
                float v = acc[mt][nt][r] + bv;
                if (EPI == 0) {
                    int bb = gm / 196, nn = gm - bb * 196;
                    int h = gn / 192, r2 = gn - h * 192;
                    int bh = bb * 8 + h;
                    if (r2 < 32)
                        o_q[((size_t)bh * 196 + nn) * 32 + r2] = f2b(v);
                    else if (r2 < 64)
                        o_k[((size_t)bh * 196 + nn) * 32 + (r2 - 32)] = f2b(v);
                    else
                        o_v[((size_t)bh * 196 + nn) * 128 + (r2 - 64)] = f2b(v);
                } else {
                    o_f[(size_t)gm * 384 + gn] = v;
                }
            }
        }
    }
}

// ---------------- fused attention per chunk-local (b,h), 8 waves ----------------
// Q,K: [bh][196][32] bf16; V: [bh][196][128] bf16 row-major (transposed in-LDS);
// bm: [8][196][196] fp32; out (chunk-local): [b*196+n][h*128+d] bf16
__global__ __launch_bounds__(512) void attn_kernel(
    const u16* __restrict__ qb, const u16* __restrict__ kb, const u16* __restrict__ vb,
    const float* __restrict__ bm, u16* __restrict__ out) {
    __shared__ u16 Klds[224 * 40];     // padded stride 40
    __shared__ u16 Vlds[128 * 232];    // V^T: rows d, cols k (padded 232)
    __shared__ u16 Plds[8][16 * 232];  // per-wave P tile

    const int bh = blockIdx.x;  // chunk-local
    const int b = bh >> 3, h = bh & 7;
    const int tid = threadIdx.x, wave = tid >> 6, lane = tid & 63;
    const int l15 = lane & 15, l4 = lane >> 4;

    // zero Vlds (covers k >= 196 padding)
    for (int u = tid; u < (128 * 232) / 8; u += 512)
        reinterpret_cast<short8*>(Vlds)[u] = short8{};
    // stage K (zero-fill rows >= 196)
    const u16* kbase = kb + (size_t)bh * (196 * 32);
    for (int u = tid; u < 896; u += 512) {
        int j = u >> 2, c8 = (u & 3) * 8;
        short8 v = {};
        if (j < 196) v = *reinterpret_cast<const short8*>(kbase + j * 32 + c8);
        *reinterpret_cast<short8*>(&Klds[j * 40 + c8]) = v;
    }
    __syncthreads();
    // transposed V stage: V[k][d] (coalesced read) -> Vlds[d][k]
    const u16* vbase = vb + (size_t)bh * (196 * 128);
    for (int u0 = tid; u0 < 3136; u0 += 512) {  // 3136 = 196*128/8
        int k = u0 >> 4;
        int d0 = (u0 & 15) * 8;
        short8 vv = *reinterpret_cast<const short8*>(vbase + k * 128 + d0);
#pragma unroll
        for (int j = 0; j < 8; j++) Vlds[(d0 + j) * 232 + k] = (u16)vv[j];
    }
    __syncthreads();

    const float* bmh = bm + h * (196 * 196);
    const u16* qbase = qb + (size_t)bh * (196 * 32);
    u16* P = &Plds[wave][0];

    for (int it = wave; it < 13; it += 8) {
        int i0 = it * 16;
        int qn = i0 + l15; if (qn > 195) qn = 195;
        short8 qf = *reinterpret_cast<const short8*>(qbase + qn * 32 + l4 * 8);

        f32x4 s[13];
#pragma unroll
        for (int jt = 0; jt < 13; jt++) {
            short8 kf = *reinterpret_cast<const short8*>(&Klds[(jt * 16 + l15) * 40 + l4 * 8]);
            f32x4 z = {0.f, 0.f, 0.f, 0.f};
            s[jt] = mfma16(qf, kf, z);
        }

#pragma unroll
        for (int r = 0; r < 4; r++) {
            int gi = i0 + l4 * 4 + r;
            int girow = gi < 196 ? gi : 195;
            float mx = -3e38f;
#pragma unroll
            for (int jt = 0; jt < 13; jt++) {
                int gj = jt * 16 + l15;
                float v = (gj < 196) ? (s[jt][r] * SCALE_QK + bmh[girow * 196 + gj]) : -3e38f;
                s[jt][r] = v;
                mx = fmaxf(mx, v);
            }
            mx = fmaxf(mx, __shfl_xor(mx, 1));
            mx = fmaxf(mx, __shfl_xor(mx, 2));
            mx = fmaxf(mx, __shfl_xor(mx, 4));
            mx = fmaxf(mx, __shfl_xor(mx, 8));
            float sum = 0.f;
#pragma unroll
            for (int jt = 0; jt < 13; jt++) {
                float p = __expf(s[jt][r] - mx);
                s[jt][r] = p;
                sum += p;
            }
            sum += __shfl_xor(sum, 1);
            sum += __shfl_xor(sum, 2);
            sum += __shfl_xor(sum, 4);
            sum += __shfl_xor(sum, 8);
            float inv = 1.f / sum;
#pragma unroll
            for (int jt = 0; jt < 13; jt++) s[jt][r] *= inv;
        }

        // write P (bf16) to per-wave LDS
#pragma unroll
        for (int jt = 0; jt < 13; jt++) {
#pragma unroll
            for (int r = 0; r < 4; r++)
                P[(l4 * 4 + r) * 232 + jt * 16 + l15] = f2b(s[jt][r]);
        }
#pragma unroll
        for (int r = 0; r < 4; r++) P[(l4 * 4 + r) * 232 + 208 + l15] = 0;

        // PV
        f32x4 o[8] = {};
#pragma unroll
        for (int ks = 0; ks < 7; ks++) {
            short8 pf = *reinterpret_cast<const short8*>(&P[l15 * 232 + ks * 32 + l4 * 8]);
#pragma unroll
            for (int dt = 0; dt < 8; dt++) {
                short8 vf = *reinterpret_cast<const short8*>(
                    &Vlds[(dt * 16 + l15) * 232 + ks * 32 + l4 * 8]);
                o[dt] = mfma16(pf, vf, o[dt]);
            }
        }

        // store O as bf16 into chunk-local [token][h*128+d]
        u16* ob = out + ((size_t)b * 196) * 1024 + h * 128;
#pragma unroll
        for (int dt = 0; dt < 8; dt++) {
#pragma unroll
            for (int r = 0; r < 4; r++) {
                int gi = i0 + l4 * 4 + r;
                if (gi < 196) ob[(size_t)gi * 1024 + dt * 16 + l15] = f2b(o[dt][r]);
            }
        }
    }
}

extern "C" void kernel_launch(void* const* d_in, const int* in_sizes, int n_in,
                              void* d_out, int out_size, void* d_ws, size_t ws_size,
                              hipStream_t stream) {
    const float* x = (const float*)d_in[0];
    const float* w_qkv = (const float*)d_in[1];
    const float* b_qkv = (const float*)d_in[2];
    const float* w_proj = (const float*)d_in[3];
    const float* b_proj = (const float*)d_in[4];
    const float* attn_biases = (const float*)d_in[5];
    const int* bias_idxs = (const int*)d_in[6];
    float* out = (float*)d_out;

    // runtime workspace plan (ws_size fixed across calls -> deterministic)
    const size_t MB = 1ull << 20;
    int nc;
    bool full_aout;
    if (ws_size >= 310 * MB)      { nc = 1; full_aout = true; }
    else if (ws_size >= 165 * MB) { nc = 4; full_aout = true; }
    else                          { nc = 4; full_aout = false; }
    const int cb = 256 / nc;
    const size_t chm = (size_t)cb * 196;
    const int chbh = cb * 8;

    char* p = (char*)d_ws;
    auto alloc = [&](size_t bytes) {
        void* r = (void*)p;
        p += (bytes + 255) & ~(size_t)255;
        return r;
    };
    // persistent (~3.2 MB)
    u16* wqb = (u16*)alloc(1536ull * 384 * 2);
    u16* wpb = (u16*)alloc(384ull * 1024 * 2);
    float* bmat = (float*)alloc(8ull * 196 * 196 * 4);
    // chunk buffers
    u16* xbc = (u16*)alloc(chm * 384 * 2);
    u16* qc = (u16*)alloc((size_t)chbh * 196 * 32 * 2);
    u16* kc = (u16*)alloc((size_t)chbh * 196 * 32 * 2);
    u16* vc = (u16*)alloc((size_t)chbh * 196 * 128 * 2);
    u16* aout_b = (u16*)alloc((full_aout ? 50176ull : chm) * 1024 * 2);

    // one-time prep
    cvt_kernel<<<576, 256, 0, stream>>>((const float4*)w_qkv, (ushort4*)wqb, 1536 * 384 / 4);
    cvt_kernel<<<384, 256, 0, stream>>>((const float4*)w_proj, (ushort4*)wpb, 384 * 1024 / 4);
    biasmat_kernel<<<1201, 256, 0, stream>>>(attn_biases, bias_idxs, bmat);

    const int qkv_grid = (int)(chm / 128) * 12;
    const int proj_grid_chunk = (int)(chm / 128) * 3;

    for (int c = 0; c < nc; ++c) {
        const float* xc = x + (size_t)c * chm * 384;
        cvt_kernel<<<1024, 256, 0, stream>>>((const float4*)xc, (ushort4*)xbc,
                                             (int)(chm * 384 / 4));
        gemm_kernel<384, 12, 0><<<qkv_grid, 256, 0, stream>>>(xbc, wqb, b_qkv, qc, kc, vc,
                                                              nullptr);
        u16* aoutc = aout_b + (full_aout ? (size_t)c * chm * 1024 : 0);
        attn_kernel<<<chbh, 512, 0, stream>>>(qc, kc, vc, bmat, aoutc);
        if (!full_aout) {
            gemm_kernel<1024, 3, 1><<<proj_grid_chunk, 256, 0, stream>>>(
                aoutc, wpb, b_proj, nullptr, nullptr, nullptr, out + (size_t)c * chm * 384);
        }
    }
    if (full_aout) {
        gemm_kernel<1024, 3, 1><<<392 * 3, 256, 0, stream>>>(aout_b, wpb, b_proj, nullptr,
                                                             nullptr, nullptr, out);
    }
}

// Round 6
// 402.565 us; speedup vs baseline: 1.4638x; 1.0091x over previous
//
#include <hip/hip_runtime.h>

typedef unsigned short u16;
typedef short short8 __attribute__((ext_vector_type(8)));
typedef float f32x4 __attribute__((ext_vector_type(4)));
typedef __bf16 bf16x8 __attribute__((ext_vector_type(8)));

#define SCALE_QK 0.17677669529663687f  // 1/sqrt(32)

__device__ __forceinline__ u16 f2b(float f) {
    unsigned int u = __builtin_bit_cast(unsigned int, f);
    u += 0x7fffu + ((u >> 16) & 1u);
    return (u16)(u >> 16);
}

__device__ __forceinline__ f32x4 mfma16(short8 a, short8 b, f32x4 c) {
    return __builtin_amdgcn_mfma_f32_16x16x32_bf16(
        __builtin_bit_cast(bf16x8, a), __builtin_bit_cast(bf16x8, b), c, 0, 0, 0);
}

__device__ __forceinline__ void gload_lds16(const u16* g, u16* l) {
    __builtin_amdgcn_global_load_lds(
        (const __attribute__((address_space(1))) unsigned int*)g,
        (__attribute__((address_space(3))) unsigned int*)l, 16, 0, 0);
}

// bijective XCD-chunked block-id swizzle (m204)
__device__ __forceinline__ int xcd_swizzle(int bid, int nwg) {
    int qd = nwg >> 3, rm = nwg & 7;
    int xcd = bid & 7, lo = bid >> 3;
    return (xcd < rm ? xcd * (qd + 1) : rm * (qd + 1) + (xcd - rm) * qd) + lo;
}

// ---------------- fp32 -> bf16 convert ----------------
__global__ void cvt_kernel(const float4* __restrict__ in, ushort4* __restrict__ out, int n4) {
    int stride = gridDim.x * blockDim.x;
    for (int i = blockIdx.x * blockDim.x + threadIdx.x; i < n4; i += stride) {
        float4 v = in[i];
        ushort4 o;
        o.x = f2b(v.x); o.y = f2b(v.y); o.z = f2b(v.z); o.w = f2b(v.w);
        out[i] = o;
    }
}

// ---------------- bias matrix expand: bm[h][i][j] = ab[h][idx[i][j]] ----------------
__global__ void biasmat_kernel(const float* __restrict__ ab, const int* __restrict__ idxs,
                               float* __restrict__ bm) {
    int total = 8 * 196 * 196;
    int stride = gridDim.x * blockDim.x;
    for (int i = blockIdx.x * blockDim.x + threadIdx.x; i < total; i += stride) {
        int h = i / (196 * 196);
        int ij = i - h * (196 * 196);
        bm[i] = ab[h * 196 + idxs[ij]];
    }
}

// ---------------- bf16 GEMM: C = A(M x K) * Bw(N x K)^T + bias ----------------
// 128x128 tile, 4 waves (64x64 each), BK=32, THREE LDS buffers with 2-deep
// counted-vmcnt prefetch (stage t+2 during compute t; vmcnt(8) retires tile t).
// Bank swizzle: slot ^= (row>>1)&3  ->  bank-quad = 4*(row&1) + (l4^f) covers
// all 8 quads x 2 lanes = 2-way (free).  XCD-chunked block swizzle.
// EPI==0: route outputs to q/k/v (qkv, chunk-local).  EPI==1: fp32 out (proj).
template <int KDIM, int NTILES, int EPI>
__global__ __launch_bounds__(256) void gemm_kernel(
    const u16* __restrict__ A, const u16* __restrict__ Bw, const float* __restrict__ bias,
    u16* __restrict__ o_q, u16* __restrict__ o_k, u16* __restrict__ o_v,
    float* __restrict__ o_f) {
    __shared__ u16 Asl[3][128 * 32];
    __shared__ u16 Bsl[3][128 * 32];

    const int wg = xcd_swizzle(blockIdx.x, gridDim.x);
    const int tm = wg / NTILES, tn = wg % NTILES;
    const int tid = threadIdx.x, wave = tid >> 6, lane = tid & 63;
    const int l15 = lane & 15, l4 = lane >> 4;
    const int wm = (wave >> 1) * 64, wn = (wave & 1) * 64;

    const u16* Ab = A + (size_t)tm * 128 * KDIM;
    const u16* Bb = Bw + (size_t)tn * 128 * KDIM;

    f32x4 acc[4][4] = {};

    // stage one BK=32 tile (A+B): 2+2 global_load_lds per wave.
    // lane l: row = w*32 + i*16 + (l>>2); source chunk pre-swizzled (l&3)^f(row).
    auto stage = [&](int buf, int k0) {
#pragma unroll
        for (int i = 0; i < 2; i++) {
            int row = wave * 32 + i * 16 + (lane >> 2);
            int sc = (lane & 3) ^ ((row >> 1) & 3);
            gload_lds16(Ab + (size_t)row * KDIM + k0 + sc * 8,
                        &Asl[buf][(wave * 32 + i * 16) * 32]);
            gload_lds16(Bb + (size_t)row * KDIM + k0 + sc * 8,
                        &Bsl[buf][(wave * 32 + i * 16) * 32]);
        }
    };

    constexpr int NT = KDIM / 32;
    stage(0, 0);
    stage(1, 32);
#pragma unroll
    for (int t = 0; t < NT; ++t) {
        if (t + 2 < NT) {
            stage((t + 2) % 3, (t + 2) * 32);
            asm volatile("s_waitcnt vmcnt(8)" ::: "memory");  // tile t landed; t+1,t+2 in flight
        } else if (t + 1 < NT) {
            asm volatile("s_waitcnt vmcnt(4)" ::: "memory");  // tile t landed; t+1 in flight
        } else {
            asm volatile("s_waitcnt vmcnt(0)" ::: "memory");
        }
        __builtin_amdgcn_s_barrier();

        const char* As = (const char*)Asl[t % 3];
        const char* Bs = (const char*)Bsl[t % 3];
        short8 af[4], bfr[4];
#pragma unroll
        for (int u = 0; u < 4; u++) {
            int rowa = wm + u * 16 + l15;
            int bytea = rowa * 64 + ((l4 * 16) ^ (((rowa >> 1) & 3) << 4));
            af[u] = *reinterpret_cast<const short8*>(As + bytea);
            int rowb = wn + u * 16 + l15;
            int byteb = rowb * 64 + ((l4 * 16) ^ (((rowb >> 1) & 3) << 4));
            bfr[u] = *reinterpret_cast<const short8*>(Bs + byteb);
        }
        __builtin_amdgcn_s_setprio(1);
#pragma unroll
        for (int mt = 0; mt < 4; mt++)
#pragma unroll
            for (int nt = 0; nt < 4; nt++)
                acc[mt][nt] = mfma16(af[mt], bfr[nt], acc[mt][nt]);
        __builtin_amdgcn_s_setprio(0);
        __builtin_amdgcn_s_barrier();
    }

    // epilogue (all stores coalesced over l15)
#pragma unroll
    for (int mt = 0; mt < 4; mt++) {
#pragma unroll
        for (int nt = 0; nt < 4; nt++) {
            int gn = tn * 128 + wn + nt * 16 + l15;
            float bv = bias[gn];
#pragma unroll
            for (int r = 0; r < 4; r++) {
                int gm = tm * 128 + wm + mt * 16 + l4 * 4 + r;  // chunk-local token row
                float v = acc[mt][nt][r] + bv;
                if (EPI == 0) {
                    int bb = gm / 196, nn = gm - bb * 196;
                    int h = gn / 192, r2 = gn - h * 192;
                    int bh = bb * 8 + h;
                    if (r2 < 32)
                        o_q[((size_t)bh * 196 + nn) * 32 + r2] = f2b(v);
                    else if (r2 < 64)
                        o_k[((size_t)bh * 196 + nn) * 32 + (r2 - 32)] = f2b(v);
                    else
                        o_v[((size_t)bh * 196 + nn) * 128 + (r2 - 64)] = f2b(v);
                } else {
                    o_f[(size_t)gm * 384 + gn] = v;
                }
            }
        }
    }
}

// ---------------- fused attention per chunk-local (b,h), 8 waves ----------------
// Q,K: [bh][196][32] bf16; V: [bh][196][128] bf16 row-major (transposed in-LDS);
// bm: [8][196][196] fp32; out (chunk-local): [b*196+n][h*128+d] bf16
__global__ __launch_bounds__(512) void attn_kernel(
    const u16* __restrict__ qb, const u16* __restrict__ kb, const u16* __restrict__ vb,
    const float* __restrict__ bm, u16* __restrict__ out) {
    __shared__ u16 Klds[224 * 40];     // padded stride 40
    __shared__ u16 Vlds[128 * 232];    // V^T: rows d, cols k (padded 232)
    __shared__ u16 Plds[8][16 * 232];  // per-wave P tile

    const int bh = blockIdx.x;  // chunk-local
    const int b = bh >> 3, h = bh & 7;
    const int tid = threadIdx.x, wave = tid >> 6, lane = tid & 63;
    const int l15 = lane & 15, l4 = lane >> 4;

    // zero Vlds (covers k >= 196 padding)
    for (int u = tid; u < (128 * 232) / 8; u += 512)
        reinterpret_cast<short8*>(Vlds)[u] = short8{};
    // stage K (zero-fill rows >= 196)
    const u16* kbase = kb + (size_t)bh * (196 * 32);
    for (int u = tid; u < 896; u += 512) {
        int j = u >> 2, c8 = (u & 3) * 8;
        short8 v = {};
        if (j < 196) v = *reinterpret_cast<const short8*>(kbase + j * 32 + c8);
        *reinterpret_cast<short8*>(&Klds[j * 40 + c8]) = v;
    }
    __syncthreads();
    // transposed V stage: V[k][d] (coalesced read) -> Vlds[d][k]
    const u16* vbase = vb + (size_t)bh * (196 * 128);
    for (int u0 = tid; u0 < 3136; u0 += 512) {  // 3136 = 196*128/8
        int k = u0 >> 4;
        int d0 = (u0 & 15) * 8;
        short8 vv = *reinterpret_cast<const short8*>(vbase + k * 128 + d0);
#pragma unroll
        for (int j = 0; j < 8; j++) Vlds[(d0 + j) * 232 + k] = (u16)vv[j];
    }
    __syncthreads();

    const float* bmh = bm + h * (196 * 196);
    const u16* qbase = qb + (size_t)bh * (196 * 32);
    u16* P = &Plds[wave][0];

    for (int it = wave; it < 13; it += 8) {
        int i0 = it * 16;
        int qn = i0 + l15; if (qn > 195) qn = 195;
        short8 qf = *reinterpret_cast<const short8*>(qbase + qn * 32 + l4 * 8);

        f32x4 s[13];
#pragma unroll
        for (int jt = 0; jt < 13; jt++) {
            short8 kf = *reinterpret_cast<const short8*>(&Klds[(jt * 16 + l15) * 40 + l4 * 8]);
            f32x4 z = {0.f, 0.f, 0.f, 0.f};
            s[jt] = mfma16(qf, kf, z);
        }

#pragma unroll
        for (int r = 0; r < 4; r++) {
            int gi = i0 + l4 * 4 + r;
            int girow = gi < 196 ? gi : 195;
            float mx = -3e38f;
#pragma unroll
            for (int jt = 0; jt < 13; jt++) {
                int gj = jt * 16 + l15;
                float v = (gj < 196) ? (s[jt][r] * SCALE_QK + bmh[girow * 196 + gj]) : -3e38f;
                s[jt][r] = v;
                mx = fmaxf(mx, v);
            }
            mx = fmaxf(mx, __shfl_xor(mx, 1));
            mx = fmaxf(mx, __shfl_xor(mx, 2));
            mx = fmaxf(mx, __shfl_xor(mx, 4));
            mx = fmaxf(mx, __shfl_xor(mx, 8));
            float sum = 0.f;
#pragma unroll
            for (int jt = 0; jt < 13; jt++) {
                float p = __expf(s[jt][r] - mx);
                s[jt][r] = p;
                sum += p;
            }
            sum += __shfl_xor(sum, 1);
            sum += __shfl_xor(sum, 2);
            sum += __shfl_xor(sum, 4);
            sum += __shfl_xor(sum, 8);
            float inv = 1.f / sum;
#pragma unroll
            for (int jt = 0; jt < 13; jt++) s[jt][r] *= inv;
        }

        // write P (bf16) to per-wave LDS
#pragma unroll
        for (int jt = 0; jt < 13; jt++) {
#pragma unroll
            for (int r = 0; r < 4; r++)
                P[(l4 * 4 + r) * 232 + jt * 16 + l15] = f2b(s[jt][r]);
        }
#pragma unroll
        for (int r = 0; r < 4; r++) P[(l4 * 4 + r) * 232 + 208 + l15] = 0;

        // PV
        f32x4 o[8] = {};
#pragma unroll
        for (int ks = 0; ks < 7; ks++) {
            short8 pf = *reinterpret_cast<const short8*>(&P[l15 * 232 + ks * 32 + l4 * 8]);
#pragma unroll
            for (int dt = 0; dt < 8; dt++) {
                short8 vf = *reinterpret_cast<const short8*>(
                    &Vlds[(dt * 16 + l15) * 232 + ks * 32 + l4 * 8]);
                o[dt] = mfma16(pf, vf, o[dt]);
            }
        }

        // store O as bf16 into chunk-local [token][h*128+d]
        u16* ob = out + ((size_t)b * 196) * 1024 + h * 128;
#pragma unroll
        for (int dt = 0; dt < 8; dt++) {
#pragma unroll
            for (int r = 0; r < 4; r++) {
                int gi = i0 + l4 * 4 + r;
                if (gi < 196) ob[(size_t)gi * 1024 + dt * 16 + l15] = f2b(o[dt][r]);
            }
        }
    }
}

extern "C" void kernel_launch(void* const* d_in, const int* in_sizes, int n_in,
                              void* d_out, int out_size, void* d_ws, size_t ws_size,
                              hipStream_t stream) {
    const float* x = (const float*)d_in[0];
    const float* w_qkv = (const float*)d_in[1];
    const float* b_qkv = (const float*)d_in[2];
    const float* w_proj = (const float*)d_in[3];
    const float* b_proj = (const float*)d_in[4];
    const float* attn_biases = (const float*)d_in[5];
    const int* bias_idxs = (const int*)d_in[6];
    float* out = (float*)d_out;

    // runtime workspace plan (ws_size fixed across calls -> deterministic)
    const size_t MB = 1ull << 20;
    int nc;
    bool full_aout;
    if (ws_size >= 310 * MB)      { nc = 1; full_aout = true; }
    else if (ws_size >= 165 * MB) { nc = 4; full_aout = true; }
    else                          { nc = 4; full_aout = false; }
    const int cb = 256 / nc;
    const size_t chm = (size_t)cb * 196;
    const int chbh = cb * 8;

    char* p = (char*)d_ws;
    auto alloc = [&](size_t bytes) {
        void* r = (void*)p;
        p += (bytes + 255) & ~(size_t)255;
        return r;
    };
    // persistent (~3.2 MB)
    u16* wqb = (u16*)alloc(1536ull * 384 * 2);
    u16* wpb = (u16*)alloc(384ull * 1024 * 2);
    float* bmat = (float*)alloc(8ull * 196 * 196 * 4);
    // chunk buffers
    u16* xbc = (u16*)alloc(chm * 384 * 2);
    u16* qc = (u16*)alloc((size_t)chbh * 196 * 32 * 2);
    u16* kc = (u16*)alloc((size_t)chbh * 196 * 32 * 2);
    u16* vc = (u16*)alloc((size_t)chbh * 196 * 128 * 2);
    u16* aout_b = (u16*)alloc((full_aout ? 50176ull : chm) * 1024 * 2);

    // one-time prep
    cvt_kernel<<<576, 256, 0, stream>>>((const float4*)w_qkv, (ushort4*)wqb, 1536 * 384 / 4);
    cvt_kernel<<<384, 256, 0, stream>>>((const float4*)w_proj, (ushort4*)wpb, 384 * 1024 / 4);
    biasmat_kernel<<<1201, 256, 0, stream>>>(attn_biases, bias_idxs, bmat);

    const int qkv_grid = (int)(chm / 128) * 12;
    const int proj_grid_chunk = (int)(chm / 128) * 3;

    for (int c = 0; c < nc; ++c) {
        const float* xc = x + (size_t)c * chm * 384;
        cvt_kernel<<<1024, 256, 0, stream>>>((const float4*)xc, (ushort4*)xbc,
                                             (int)(chm * 384 / 4));
        gemm_kernel<384, 12, 0><<<qkv_grid, 256, 0, stream>>>(xbc, wqb, b_qkv, qc, kc, vc,
                                                              nullptr);
        u16* aoutc = aout_b + (full_aout ? (size_t)c * chm * 1024 : 0);
        attn_kernel<<<chbh, 512, 0, stream>>>(qc, kc, vc, bmat, aoutc);
        if (!full_aout) {
            gemm_kernel<1024, 3, 1><<<proj_grid_chunk, 256, 0, stream>>>(
                aoutc, wpb, b_proj, nullptr, nullptr, nullptr, out + (size_t)c * chm * 384);
        }
    }
    if (full_aout) {
        gemm_kernel<1024, 3, 1><<<392 * 3, 256, 0, stream>>>(aout_b, wpb, b_proj, nullptr,
                                                             nullptr, nullptr, out);
    }
}

// Round 7
// 380.854 us; speedup vs baseline: 1.5472x; 1.0570x over previous
//
#include <hip/hip_runtime.h>

typedef unsigned short u16;
typedef short short8 __attribute__((ext_vector_type(8)));
typedef float f32x4 __attribute__((ext_vector_type(4)));
typedef __bf16 bf16x8 __attribute__((ext_vector_type(8)));

#define SCALE_QK 0.17677669529663687f  // 1/sqrt(32)

__device__ __forceinline__ u16 f2b(float f) {
    unsigned int u = __builtin_bit_cast(unsigned int, f);
    u += 0x7fffu + ((u >> 16) & 1u);
    return (u16)(u >> 16);
}

__device__ __forceinline__ f32x4 mfma16(short8 a, short8 b, f32x4 c) {
    return __builtin_amdgcn_mfma_f32_16x16x32_bf16(
        __builtin_bit_cast(bf16x8, a), __builtin_bit_cast(bf16x8, b), c, 0, 0, 0);
}

__device__ __forceinline__ void gload_lds16(const u16* g, u16* l) {
    __builtin_amdgcn_global_load_lds(
        (const __attribute__((address_space(1))) unsigned int*)g,
        (__attribute__((address_space(3))) unsigned int*)l, 16, 0, 0);
}

// bijective XCD-chunked block-id swizzle (m204)
__device__ __forceinline__ int xcd_swizzle(int bid, int nwg) {
    int qd = nwg >> 3, rm = nwg & 7;
    int xcd = bid & 7, lo = bid >> 3;
    return (xcd < rm ? xcd * (qd + 1) : rm * (qd + 1) + (xcd - rm) * qd) + lo;
}

// ---------------- fp32 -> bf16 convert ----------------
__global__ void cvt_kernel(const float4* __restrict__ in, ushort4* __restrict__ out, int n4) {
    int stride = gridDim.x * blockDim.x;
    for (int i = blockIdx.x * blockDim.x + threadIdx.x; i < n4; i += stride) {
        float4 v = in[i];
        ushort4 o;
        o.x = f2b(v.x); o.y = f2b(v.y); o.z = f2b(v.z); o.w = f2b(v.w);
        out[i] = o;
    }
}

// ---------------- bias matrix expand: bm[h][i][j] = ab[h][idx[i][j]] ----------------
__global__ void biasmat_kernel(const float* __restrict__ ab, const int* __restrict__ idxs,
                               float* __restrict__ bm) {
    int total = 8 * 196 * 196;
    int stride = gridDim.x * blockDim.x;
    for (int i = blockIdx.x * blockDim.x + threadIdx.x; i < total; i += stride) {
        int h = i / (196 * 196);
        int ij = i - h * (196 * 196);
        bm[i] = ab[h * 196 + idxs[ij]];
    }
}

// ---------------- bf16 GEMM: C = A(M x K) * Bw(N x K)^T + bias ----------------
// 128x128 tile, 4 waves (64x64 each), BK=32, THREE LDS buffers with 2-deep
// counted-vmcnt prefetch (stage t+2 during compute t; vmcnt(8) retires tile t).
// Bank swizzle: slot ^= (row>>1)&3 -> balanced bank quads (conflict-free, r6 PMC).
// EPI==0: route outputs to q/k/v (qkv, chunk-local).  EPI==1: fp32 out (proj).
template <int KDIM, int NTILES, int EPI>
__global__ __launch_bounds__(256) void gemm_kernel(
    const u16* __restrict__ A, const u16* __restrict__ Bw, const float* __restrict__ bias,
    u16* __restrict__ o_q, u16* __restrict__ o_k, u16* __restrict__ o_v,
    float* __restrict__ o_f) {
    __shared__ u16 Asl[3][128 * 32];
    __shared__ u16 Bsl[3][128 * 32];

    const int wg = xcd_swizzle(blockIdx.x, gridDim.x);
    const int tm = wg / NTILES, tn = wg % NTILES;
    const int tid = threadIdx.x, wave = tid >> 6, lane = tid & 63;
    const int l15 = lane & 15, l4 = lane >> 4;
    const int wm = (wave >> 1) * 64, wn = (wave & 1) * 64;

    const u16* Ab = A + (size_t)tm * 128 * KDIM;
    const u16* Bb = Bw + (size_t)tn * 128 * KDIM;

    f32x4 acc[4][4] = {};

    auto stage = [&](int buf, int k0) {
#pragma unroll
        for (int i = 0; i < 2; i++) {
            int row = wave * 32 + i * 16 + (lane >> 2);
            int sc = (lane & 3) ^ ((row >> 1) & 3);
            gload_lds16(Ab + (size_t)row * KDIM + k0 + sc * 8,
                        &Asl[buf][(wave * 32 + i * 16) * 32]);
            gload_lds16(Bb + (size_t)row * KDIM + k0 + sc * 8,
                        &Bsl[buf][(wave * 32 + i * 16) * 32]);
        }
    };

    constexpr int NT = KDIM / 32;
    stage(0, 0);
    stage(1, 32);
#pragma unroll
    for (int t = 0; t < NT; ++t) {
        if (t + 2 < NT) {
            stage((t + 2) % 3, (t + 2) * 32);
            asm volatile("s_waitcnt vmcnt(8)" ::: "memory");  // tile t landed; t+1,t+2 in flight
        } else if (t + 1 < NT) {
            asm volatile("s_waitcnt vmcnt(4)" ::: "memory");
        } else {
            asm volatile("s_waitcnt vmcnt(0)" ::: "memory");
        }
        __builtin_amdgcn_s_barrier();

        const char* As = (const char*)Asl[t % 3];
        const char* Bs = (const char*)Bsl[t % 3];
        short8 af[4], bfr[4];
#pragma unroll
        for (int u = 0; u < 4; u++) {
            int rowa = wm + u * 16 + l15;
            int bytea = rowa * 64 + ((l4 * 16) ^ (((rowa >> 1) & 3) << 4));
            af[u] = *reinterpret_cast<const short8*>(As + bytea);
            int rowb = wn + u * 16 + l15;
            int byteb = rowb * 64 + ((l4 * 16) ^ (((rowb >> 1) & 3) << 4));
            bfr[u] = *reinterpret_cast<const short8*>(Bs + byteb);
        }
        __builtin_amdgcn_s_setprio(1);
#pragma unroll
        for (int mt = 0; mt < 4; mt++)
#pragma unroll
            for (int nt = 0; nt < 4; nt++)
                acc[mt][nt] = mfma16(af[mt], bfr[nt], acc[mt][nt]);
        __builtin_amdgcn_s_setprio(0);
        __builtin_amdgcn_s_barrier();
    }

    // epilogue (all stores coalesced over l15)
#pragma unroll
    for (int mt = 0; mt < 4; mt++) {
#pragma unroll
        for (int nt = 0; nt < 4; nt++) {
            int gn = tn * 128 + wn + nt * 16 + l15;
            float bv = bias[gn];
#pragma unroll
            for (int r = 0; r < 4; r++) {
                int gm = tm * 128 + wm + mt * 16 + l4 * 4 + r;  // chunk-local token row
                float v = acc[mt][nt][r] + bv;
                if (EPI == 0) {
                    int bb = gm / 196, nn = gm - bb * 196;
                    int h = gn / 192, r2 = gn - h * 192;
                    int bh = bb * 8 + h;
                    if (r2 < 32)
                        o_q[((size_t)bh * 196 + nn) * 32 + r2] = f2b(v);
                    else if (r2 < 64)
                        o_k[((size_t)bh * 196 + nn) * 32 + (r2 - 32)] = f2b(v);
                    else
                        o_v[((size_t)bh * 196 + nn) * 128 + (r2 - 64)] = f2b(v);
                } else {
                    o_f[(size_t)gm * 384 + gn] = v;
                }
            }
        }
    }
}

// ---------------- fused attention per chunk-local (b,h), 8 waves ----------------
// Q,K: [bh][196][32] bf16; V: [bh][196][128] bf16 row-major (transposed in-LDS);
// bm: [8][196][196] fp32; out (chunk-local): [b*196+n][h*128+d] bf16
__global__ __launch_bounds__(512) void attn_kernel(
    const u16* __restrict__ qb, const u16* __restrict__ kb, const u16* __restrict__ vb,
    const float* __restrict__ bm, u16* __restrict__ out) {
    __shared__ u16 Klds[224 * 40];     // padded stride 40
    __shared__ u16 Vlds[128 * 232];    // V^T: rows d, cols k (padded 232)
    __shared__ u16 Plds[8][16 * 232];  // per-wave P tile

    const int bh = blockIdx.x;  // chunk-local
    const int b = bh >> 3, h = bh & 7;
    const int tid = threadIdx.x, wave = tid >> 6, lane = tid & 63;
    const int l15 = lane & 15, l4 = lane >> 4;

    // zero only Vlds cols 196..223 (the region PV reads beyond real data)
    for (int u = tid; u < 128 * 28; u += 512) {
        int rw = u / 28, c = u - rw * 28;
        Vlds[rw * 232 + 196 + c] = 0;
    }
    // stage K (zero-fill rows >= 196)
    const u16* kbase = kb + (size_t)bh * (196 * 32);
    for (int u = tid; u < 896; u += 512) {
        int j = u >> 2, c8 = (u & 3) * 8;
        short8 v = {};
        if (j < 196) v = *reinterpret_cast<const short8*>(kbase + j * 32 + c8);
        *reinterpret_cast<short8*>(&Klds[j * 40 + c8]) = v;
    }
    // transposed V stage: V[k][d] (coalesced read) -> Vlds[d][k].
    // Staggered-diagonal write order: j = (jj + lane) & 7 spreads the 8 writes
    // across 8 bank groups (bank = 20*((8*lane + j) mod 8) mod 32 distinct)
    // instead of all lanes hitting one bank (was ~32-way conflict).
    const u16* vbase = vb + (size_t)bh * (196 * 128);
    for (int u0 = tid; u0 < 3136; u0 += 512) {  // 3136 = 196*128/8
        int k = u0 >> 4;
        int d0 = (u0 & 15) * 8;
        short8 vv = *reinterpret_cast<const short8*>(vbase + k * 128 + d0);
#pragma unroll
        for (int jj = 0; jj < 8; jj++) {
            int j = (jj + lane) & 7;
            Vlds[(d0 + j) * 232 + k] = (u16)vv[j];
        }
    }
    __syncthreads();

    const float* bmh = bm + h * (196 * 196);
    const u16* qbase = qb + (size_t)bh * (196 * 32);
    u16* P = &Plds[wave][0];

    for (int it = wave; it < 13; it += 8) {
        int i0 = it * 16;
        int qn = i0 + l15; if (qn > 195) qn = 195;
        short8 qf = *reinterpret_cast<const short8*>(qbase + qn * 32 + l4 * 8);

        f32x4 s[13];
        __builtin_amdgcn_s_setprio(1);
#pragma unroll
        for (int jt = 0; jt < 13; jt++) {
            short8 kf = *reinterpret_cast<const short8*>(&Klds[(jt * 16 + l15) * 40 + l4 * 8]);
            f32x4 z = {0.f, 0.f, 0.f, 0.f};
            s[jt] = mfma16(qf, kf, z);
        }
        __builtin_amdgcn_s_setprio(0);

#pragma unroll
        for (int r = 0; r < 4; r++) {
            int gi = i0 + l4 * 4 + r;
            int girow = gi < 196 ? gi : 195;
            float mx = -3e38f;
#pragma unroll
            for (int jt = 0; jt < 13; jt++) {
                int gj = jt * 16 + l15;
                float v = (gj < 196) ? (s[jt][r] * SCALE_QK + bmh[girow * 196 + gj]) : -3e38f;
                s[jt][r] = v;
                mx = fmaxf(mx, v);
            }
            mx = fmaxf(mx, __shfl_xor(mx, 1));
            mx = fmaxf(mx, __shfl_xor(mx, 2));
            mx = fmaxf(mx, __shfl_xor(mx, 4));
            mx = fmaxf(mx, __shfl_xor(mx, 8));
            float sum = 0.f;
#pragma unroll
            for (int jt = 0; jt < 13; jt++) {
                float p = __expf(s[jt][r] - mx);
                s[jt][r] = p;
                sum += p;
            }
            sum += __shfl_xor(sum, 1);
            sum += __shfl_xor(sum, 2);
            sum += __shfl_xor(sum, 4);
            sum += __shfl_xor(sum, 8);
            float inv = 1.f / sum;
#pragma unroll
            for (int jt = 0; jt < 13; jt++) s[jt][r] *= inv;
        }

        // write P (bf16) to per-wave LDS
#pragma unroll
        for (int jt = 0; jt < 13; jt++) {
#pragma unroll
            for (int r = 0; r < 4; r++)
                P[(l4 * 4 + r) * 232 + jt * 16 + l15] = f2b(s[jt][r]);
        }
#pragma unroll
        for (int r = 0; r < 4; r++) P[(l4 * 4 + r) * 232 + 208 + l15] = 0;

        // PV
        f32x4 o[8] = {};
#pragma unroll
        for (int ks = 0; ks < 7; ks++) {
            short8 pf = *reinterpret_cast<const short8*>(&P[l15 * 232 + ks * 32 + l4 * 8]);
            __builtin_amdgcn_s_setprio(1);
#pragma unroll
            for (int dt = 0; dt < 8; dt++) {
                short8 vf = *reinterpret_cast<const short8*>(
                    &Vlds[(dt * 16 + l15) * 232 + ks * 32 + l4 * 8]);
                o[dt] = mfma16(pf, vf, o[dt]);
            }
            __builtin_amdgcn_s_setprio(0);
        }

        // store O as bf16 into chunk-local [token][h*128+d]
        u16* ob = out + ((size_t)b * 196) * 1024 + h * 128;
#pragma unroll
        for (int dt = 0; dt < 8; dt++) {
#pragma unroll
            for (int r = 0; r < 4; r++) {
                int gi = i0 + l4 * 4 + r;
                if (gi < 196) ob[(size_t)gi * 1024 + dt * 16 + l15] = f2b(o[dt][r]);
            }
        }
    }
}

extern "C" void kernel_launch(void* const* d_in, const int* in_sizes, int n_in,
                              void* d_out, int out_size, void* d_ws, size_t ws_size,
                              hipStream_t stream) {
    const float* x = (const float*)d_in[0];
    const float* w_qkv = (const float*)d_in[1];
    const float* b_qkv = (const float*)d_in[2];
    const float* w_proj = (const float*)d_in[3];
    const float* b_proj = (const float*)d_in[4];
    const float* attn_biases = (const float*)d_in[5];
    const int* bias_idxs = (const int*)d_in[6];
    float* out = (float*)d_out;

    // runtime workspace plan (ws_size fixed across calls -> deterministic)
    const size_t MB = 1ull << 20;
    int nc;
    bool full_aout;
    if (ws_size >= 310 * MB)      { nc = 1; full_aout = true; }
    else if (ws_size >= 165 * MB) { nc = 4; full_aout = true; }
    else                          { nc = 4; full_aout = false; }
    const int cb = 256 / nc;
    const size_t chm = (size_t)cb * 196;
    const int chbh = cb * 8;

    char* p = (char*)d_ws;
    auto alloc = [&](size_t bytes) {
        void* r = (void*)p;
        p += (bytes + 255) & ~(size_t)255;
        return r;
    };
    // persistent (~3.2 MB)
    u16* wqb = (u16*)alloc(1536ull * 384 * 2);
    u16* wpb = (u16*)alloc(384ull * 1024 * 2);
    float* bmat = (float*)alloc(8ull * 196 * 196 * 4);
    // chunk buffers
    u16* xbc = (u16*)alloc(chm * 384 * 2);
    u16* qc = (u16*)alloc((size_t)chbh * 196 * 32 * 2);
    u16* kc = (u16*)alloc((size_t)chbh * 196 * 32 * 2);
    u16* vc = (u16*)alloc((size_t)chbh * 196 * 128 * 2);
    u16* aout_b = (u16*)alloc((full_aout ? 50176ull : chm) * 1024 * 2);

    // one-time prep
    cvt_kernel<<<576, 256, 0, stream>>>((const float4*)w_qkv, (ushort4*)wqb, 1536 * 384 / 4);
    cvt_kernel<<<384, 256, 0, stream>>>((const float4*)w_proj, (ushort4*)wpb, 384 * 1024 / 4);
    biasmat_kernel<<<1201, 256, 0, stream>>>(attn_biases, bias_idxs, bmat);

    const int qkv_grid = (int)(chm / 128) * 12;
    const int proj_grid_chunk = (int)(chm / 128) * 3;

    for (int c = 0; c < nc; ++c) {
        const float* xc = x + (size_t)c * chm * 384;
        cvt_kernel<<<1024, 256, 0, stream>>>((const float4*)xc, (ushort4*)xbc,
                                             (int)(chm * 384 / 4));
        gemm_kernel<384, 12, 0><<<qkv_grid, 256, 0, stream>>>(xbc, wqb, b_qkv, qc, kc, vc,
                                                              nullptr);
        u16* aoutc = aout_b + (full_aout ? (size_t)c * chm * 1024 : 0);
        attn_kernel<<<chbh, 512, 0, stream>>>(qc, kc, vc, bmat, aoutc);
        if (!full_aout) {
            gemm_kernel<1024, 3, 1><<<proj_grid_chunk, 256, 0, stream>>>(
                aoutc, wpb, b_proj, nullptr, nullptr, nullptr, out + (size_t)c * chm * 384);
        }
    }
    if (full_aout) {
        gemm_kernel<1024, 3, 1><<<392 * 3, 256, 0, stream>>>(aout_b, wpb, b_proj, nullptr,
                                                             nullptr, nullptr, out);
    }
}